// Round 1
// 312.243 us; speedup vs baseline: 1.0842x; 1.0842x over previous
//
#include <hip/hip_runtime.h>
#include <hip/hip_bf16.h>
#include <math.h>

#define N_IMAGE 128
#define N_REG   36
#define DIM     1024
#define MAX_WORD 60
#define OT_ITERS 20
#define MARGIN_F 0.2f
#define ALPHA_F  0.1f
#define EPS_F    1e-12f

typedef short bf16x8 __attribute__((ext_vector_type(8)));
typedef float f32x4  __attribute__((ext_vector_type(4)));
typedef float f32x2  __attribute__((ext_vector_type(2)));

// ---------------- helpers ----------------

__device__ __forceinline__ unsigned int pkbf2(float a, float b) {
    union { __hip_bfloat162 h2; unsigned int u; } cv;
    cv.h2 = __float22bfloat162_rn(make_float2(a, b));
    return cv.u;
}
__device__ __forceinline__ float lo16(unsigned int u) { return __int_as_float((int)(u << 16)); }
__device__ __forceinline__ float hi16(unsigned int u) { return __int_as_float((int)(u & 0xFFFF0000u)); }

#define SWZ(x, pat) __int_as_float(__builtin_amdgcn_ds_swizzle(__float_as_int(x), (pat)))
#define BPERM(a, x) __int_as_float(__builtin_amdgcn_ds_bpermute((a), __float_as_int(x)))
// DPP add: x += dpp_perm(x). VALU pipe, low latency.
#define DPPADD(x, ctrl) \
    ((x) + __int_as_float(__builtin_amdgcn_update_dpp(0, __float_as_int(x), (ctrl), 0xf, 0xf, true)))

// 16-lane group sum (all 16 lanes get the sum). Pure DPP/VALU.
__device__ __forceinline__ float bfly16_sum(float x) {
    x = DPPADD(x, 0xB1);    // quad_perm ^1
    x = DPPADD(x, 0x4E);    // quad_perm ^2
    x = DPPADD(x, 0x124);   // row_ror:4
    x = DPPADD(x, 0x128);   // row_ror:8
    return x;
}
// full 64-lane sum (all lanes)
__device__ __forceinline__ float bfly64_sum(float x, int xaddr) {
    x = bfly16_sum(x);
    x += SWZ(x, 0x401F);   // ^16
    x += BPERM(xaddr, x);  // ^32
    return x;
}

// ------- norms (+ optional bf16 conversion of inputs into ws, + zero d_out) -------

__global__ void norms_kernel(const float* __restrict__ im, const float* __restrict__ s,
                             float* __restrict__ inv_im, float* __restrict__ inv_cap,
                             float* __restrict__ out, int conv,
                             unsigned short* __restrict__ im16,
                             unsigned short* __restrict__ s16) {
    if (blockIdx.x == 0 && threadIdx.x == 0) { out[0] = 0.0f; out[1] = 0.0f; }
    const int NIM = N_IMAGE * N_REG;     // 4608
    const int NS  = N_IMAGE * MAX_WORD;  // 7680
    int row  = blockIdx.x * 4 + (threadIdx.x >> 6);
    int lane = threadIdx.x & 63;
    if (row >= NIM + NS) return;
    const bool isim = (row < NIM);
    const float* base = isim ? (im + (size_t)row * DIM)
                             : (s  + (size_t)(row - NIM) * DIM);
    unsigned short* dst = isim ? (im16 + (size_t)row * DIM)
                               : (s16  + (size_t)(row - NIM) * DIM);
    const float4* b4 = (const float4*)base;
    float acc = 0.0f;
    for (int k = lane; k < DIM / 4; k += 64) {
        float4 v = b4[k];
        acc += v.x * v.x + v.y * v.y + v.z * v.z + v.w * v.w;
        if (conv) {
            uint2 w2; w2.x = pkbf2(v.x, v.y); w2.y = pkbf2(v.z, v.w);
            *(uint2*)(dst + k * 4) = w2;
        }
    }
    for (int off = 32; off; off >>= 1) acc += __shfl_down(acc, off, 64);
    if (lane == 0) {
        float inv = 1.0f / (sqrtf(acc) + EPS_F);
        if (isim) inv_im[row] = inv;
        else      inv_cap[row - NIM] = inv;
    }
}

// ---------------- pair body, specialized on CT = ceil(m/16) in 1..4 ----------------
// Block = (caption i, image group of 4). Wave v owns pair (i, b0+v).
// Only the first CT 16-column groups are staged / MFMA'd / iterated in OT:
// columns w >= CT*16 would be exact zeros everywhere, so skipping them is exact.

template <bool BF16IN, int CT>
__device__ __forceinline__ void pair_body(
    const float* __restrict__ im, const float* __restrict__ s,
    const unsigned short* __restrict__ im16, const unsigned short* __restrict__ s16,
    char* smem, const float* invImS, const float* invCapS,
    int cap, int b0, int m,
    float* __restrict__ S, float* __restrict__ SOT) {

    const int tid  = threadIdx.x;
    const int lane = tid & 63;
    const int wv   = tid >> 6;
    const int q    = lane >> 4;
    const int l15  = lane & 15;
    const int q4   = tid & 15;
    const int row0 = tid >> 4;
    const int xaddr = ((lane ^ 32) << 2);

    const float mf    = (float)m;
    const float inv_m = 1.0f / mf;

    const char* sA = smem;
    const char* sB = smem + 27648;

    f32x4 acc[3 * CT];
    #pragma unroll
    for (int t = 0; t < 3 * CT; ++t) acc[t] = (f32x4){0.f, 0.f, 0.f, 0.f};

    // ---- GEMM over K=1024 in 16 chunks of 64 ----
    for (int c = 0; c < 16; ++c) {
        const int col = c * 64 + q4 * 4;
        // A: 4 images x 3 row-slots
        #pragma unroll
        for (int img = 0; img < 4; ++img) {
            #pragma unroll
            for (int j = 0; j < 3; ++j) {
                const int r = row0 + 16 * j;                 // < 48
                if (j < 2 || row0 < 4) {                     // valid iff r < 36
                    const size_t ro = (size_t)(b0 * 36 + img * 36 + r) * 1024 + col;
                    uint2 w2;
                    if (BF16IN) {
                        w2 = *(const uint2*)(im16 + ro);
                    } else {
                        float4 v = *(const float4*)(im + ro);
                        w2.x = pkbf2(v.x, v.y); w2.y = pkbf2(v.z, v.w);
                    }
                    *(uint2*)(smem + (img * 48 + r) * 144 + q4 * 8) = w2;
                }
            }
        }
        // B: only CT row-slots (rows < CT*16; for CT=4 clip to 60)
        #pragma unroll
        for (int j = 0; j < CT; ++j) {
            const int r = row0 + 16 * j;
            if (CT < 4 || j < 3 || row0 < 12) {              // r < min(CT*16, 60)
                const size_t ro = (size_t)(cap * 60 + r) * 1024 + col;
                uint2 w2;
                if (BF16IN) {
                    w2 = *(const uint2*)(s16 + ro);
                } else {
                    float4 v = *(const float4*)(s + ro);
                    w2.x = pkbf2(v.x, v.y); w2.y = pkbf2(v.z, v.w);
                }
                *(uint2*)(smem + (192 + r) * 144 + q4 * 8) = w2;
            }
        }
        __syncthreads();
        #pragma unroll
        for (int h = 0; h < 2; ++h) {
            bf16x8 bfr[CT];
            #pragma unroll
            for (int ct = 0; ct < CT; ++ct)
                bfr[ct] = *(const bf16x8*)(sB + (ct * 16 + l15) * 144 + h * 64 + q * 16);
            #pragma unroll
            for (int rt = 0; rt < 3; ++rt) {
                bf16x8 afr = *(const bf16x8*)(sA + (wv * 48 + rt * 16 + l15) * 144 + h * 64 + q * 16);
                #pragma unroll
                for (int ct = 0; ct < CT; ++ct)
                    acc[rt * CT + ct] = __builtin_amdgcn_mfma_f32_16x16x32_bf16(
                        afr, bfr[ct], acc[rt * CT + ct], 0, 0, 0);
            }
        }
        __syncthreads();
    }

    // ---- OT setup in C-layout ----
    constexpr int PK = (CT + 1) / 2;
    float icap[CT]; bool vw[CT];
    #pragma unroll
    for (int ct = 0; ct < CT; ++ct) {
        const int w = ct * 16 + l15;
        vw[ct]   = (w < m);
        icap[ct] = (w < 60) ? invCapS[w] : 0.0f;
    }

    unsigned int apk[12][PK];    // A = exp(-2C), bf16-packed; j = rt*4+p, row = rt*16+q*4+p
    float mxv[CT];
    #pragma unroll
    for (int ct = 0; ct < CT; ++ct) mxv[ct] = -3e38f;

    #pragma unroll
    for (int j = 0; j < 12; ++j) {
        const int rt = j >> 2, p = j & 3;
        const int r  = rt * 16 + q * 4 + p;                  // < 48
        const bool rowok = (rt < 2) || (q == 0);             // r < 36
        const float iir = rowok ? invImS[wv * 36 + (r < 36 ? r : 0)] : 0.0f;
        float av[CT];
        #pragma unroll
        for (int ct = 0; ct < CT; ++ct) {
            const float Mv = acc[rt * CT + ct][p];
            mxv[ct] = fmaxf(mxv[ct], rowok ? Mv : -3e38f);
            const float cv = 1.0f - Mv * iir * icap[ct];     // C = 1 - cos
            const bool ok  = rowok && vw[ct];
            av[ct] = ok ? __expf(-2.0f * cv) : 0.0f;         // A = exp(-C/beta)
        }
        #pragma unroll
        for (int pk = 0; pk < PK; ++pk)
            apk[j][pk] = pkbf2(av[2 * pk], (2 * pk + 1 < CT) ? av[2 * pk + 1] : 0.0f);
    }

    // ---- row-compress 12 -> 9 j-slots (48 padded rows -> exactly 36) ----
    // Rows 32..35 currently live at (j = 8+p, q = 0). Move row 32+q into slot
    // (j = 8, lane-group q): each lane (q,l15) pulls from lane (0,l15) of apk[8+q].
    // Row-sum/col-sum placement is arbitrary, so this is exact per cell.
    {
        const int baddr = l15 << 2;
        #pragma unroll
        for (int pk = 0; pk < PK; ++pk) {
            const int r0 = __builtin_amdgcn_ds_bpermute(baddr, (int)apk[8][pk]);
            const int r1 = __builtin_amdgcn_ds_bpermute(baddr, (int)apk[9][pk]);
            const int r2 = __builtin_amdgcn_ds_bpermute(baddr, (int)apk[10][pk]);
            const int r3 = __builtin_amdgcn_ds_bpermute(baddr, (int)apk[11][pk]);
            const int lo = (q & 1) ? r1 : r0;
            const int hi = (q & 1) ? r3 : r2;
            apk[8][pk] = (unsigned int)((q & 2) ? hi : lo);
        }
    }

    const int b = b0 + wv;
    // ---- MISA: mean_w max_r M ----
    {
        float sp = 0.0f;
        #pragma unroll
        for (int ct = 0; ct < CT; ++ct) {
            float v = mxv[ct];
            v = fmaxf(v, SWZ(v, 0x401F));
            v = fmaxf(v, BPERM(xaddr, v));
            sp += vw[ct] ? v : 0.0f;
        }
        sp = bfly64_sum(sp, xaddr);      // = 4 * sum_w colmax (q-replicated)
        if (lane == 0) S[(size_t)b * N_IMAGE + cap] = sp * inv_m * 0.25f;
    }

    // ---- IPOT: 20 iterations, 9 row-slots, packed-f32 (v_pk_*) math ----
    f32x2 t2[9][PK];                     // t = T/sigma, ct-pairs packed
    f32x2 sig2[PK];
    #pragma unroll
    for (int pk = 0; pk < PK; ++pk) {
        const bool v0 = vw[2 * pk];
        const bool v1 = (2 * pk + 1 < CT) && vw[2 * pk + 1];
        sig2[pk].x = v0 ? inv_m : 0.0f;
        sig2[pk].y = v1 ? inv_m : 0.0f;
        #pragma unroll
        for (int j = 0; j < 9; ++j) {
            t2[j][pk].x = v0 ? mf : 0.0f;
            t2[j][pk].y = v1 ? mf : 0.0f;
        }
    }

    for (int it = 0; it < OT_ITERS; ++it) {
        f32x2 s2[PK], csum[PK];
        #pragma unroll
        for (int pk = 0; pk < PK; ++pk) {
            s2[pk]   = sig2[pk] * sig2[pk];
            csum[pk] = (f32x2){0.0f, 0.0f};
        }
        #pragma unroll
        for (int j = 0; j < 9; ++j) {
            f32x2 at[PK];
            #pragma unroll
            for (int pk = 0; pk < PK; ++pk) {
                f32x2 a2;
                a2.x = lo16(apk[j][pk]);
                a2.y = hi16(apk[j][pk]);
                at[pk] = a2 * t2[j][pk];                     // v_pk_mul_f32
            }
            f32x2 u2 = at[0] * s2[0];
            #pragma unroll
            for (int pk = 1; pk < PK; ++pk) u2 += at[pk] * s2[pk];   // v_pk_fma_f32
            const float R  = bfly16_sum(u2.x + u2.y);        // row-sum: Σ_w Qσ
            const float dl = __builtin_amdgcn_rcpf(36.0f * R);
            f32x2 dl2; dl2.x = dl; dl2.y = dl;
            #pragma unroll
            for (int pk = 0; pk < PK; ++pk) {
                const f32x2 tn = at[pk] * (dl2 * sig2[pk]);  // t_new = δQ
                t2[j][pk] = tn;
                csum[pk] += tn;
            }
        }
        #pragma unroll
        for (int pk = 0; pk < PK; ++pk) {
            float cx = csum[pk].x;
            cx += SWZ(cx, 0x401F);                           // ^16 (across q)
            cx += BPERM(xaddr, cx);                          // ^32
            float cy = csum[pk].y;
            cy += SWZ(cy, 0x401F);
            cy += BPERM(xaddr, cy);
            const bool v0 = vw[2 * pk];
            const bool v1 = (2 * pk + 1 < CT) && vw[2 * pk + 1];
            sig2[pk].x = v0 ? __builtin_amdgcn_rcpf(mf * cx) : 0.0f;
            sig2[pk].y = v1 ? __builtin_amdgcn_rcpf(mf * cy) : 0.0f;
        }
    }

    // ---- sims_ot = -Σ C∘T ;  C = -0.5 ln(A), T = t*sig ----
    {
        float pp = 0.0f;
        #pragma unroll
        for (int j = 0; j < 9; ++j) {
            #pragma unroll
            for (int pk = 0; pk < PK; ++pk) {
                const float ax = lo16(apk[j][pk]);
                const float cvx = -0.5f * __logf(fmaxf(ax, 1e-30f));
                pp = fmaf(cvx, t2[j][pk].x * sig2[pk].x, pp);
                if (2 * pk + 1 < CT) {
                    const float ay = hi16(apk[j][pk]);
                    const float cvy = -0.5f * __logf(fmaxf(ay, 1e-30f));
                    pp = fmaf(cvy, t2[j][pk].y * sig2[pk].y, pp);
                }
            }
        }
        pp = bfly64_sum(pp, xaddr);      // every cell counted once
        if (lane == 0) SOT[(size_t)b * N_IMAGE + cap] = -pp;
    }
}

template <bool BF16IN>
__global__ __launch_bounds__(256, 4)
void pair_kernel(const float* __restrict__ im, const float* __restrict__ s,
                 const unsigned short* __restrict__ im16,
                 const unsigned short* __restrict__ s16,
                 const int* __restrict__ s_l,
                 const float* __restrict__ inv_im, const float* __restrict__ inv_cap,
                 float* __restrict__ S, float* __restrict__ SOT) {
    const int cap = blockIdx.x;
    const int b0  = blockIdx.y * 4;
    const int tid = threadIdx.x;

    __shared__ __align__(16) char smem[36864];
    __shared__ float invImS[144];
    __shared__ float invCapS[60];

    if (tid < 144) invImS[tid] = inv_im[b0 * 36 + tid];
    else if (tid < 204) invCapS[tid - 144] = inv_cap[cap * 60 + (tid - 144)];

    const int m = s_l[cap];              // n_word, 10..60 (uniform per block)

    // zero staging once: pad rows (A r>=36, B r>=60/CT*16) must be 0 for MFMA.
    {
        float4 z = make_float4(0.f, 0.f, 0.f, 0.f);
        #pragma unroll
        for (int j = 0; j < 9; ++j)
            *(float4*)(smem + (tid + j * 256) * 16) = z;
    }
    __syncthreads();

    const int CT = __builtin_amdgcn_readfirstlane((m + 15) >> 4);   // 1..4
    switch (CT) {
    case 1: pair_body<BF16IN, 1>(im, s, im16, s16, smem, invImS, invCapS, cap, b0, m, S, SOT); break;
    case 2: pair_body<BF16IN, 2>(im, s, im16, s16, smem, invImS, invCapS, cap, b0, m, S, SOT); break;
    case 3: pair_body<BF16IN, 3>(im, s, im16, s16, smem, invImS, invCapS, cap, b0, m, S, SOT); break;
    default: pair_body<BF16IN, 4>(im, s, im16, s16, smem, invImS, invCapS, cap, b0, m, S, SOT); break;
    }
}

// ---------------- loss: 128 blocks, one per row/col pair, atomic accumulate ----

__global__ void loss_kernel(const float* __restrict__ S, const float* __restrict__ SOT,
                            float* __restrict__ out) {
    const int j = blockIdx.x;
    const int t = threadIdx.x;           // 128 threads
    __shared__ float sh[4][2];
    const float db  = S[j * 129];        // diag
    const float dob = SOT[j * 129];
    float rv = 0.f, rov = 0.f, cv = 0.f, cov = 0.f;
    if (t != j) {
        float cs  = fmaxf(0.0f, MARGIN_F + S[j * 128 + t] - db);
        float cso = fmaxf(0.0f, MARGIN_F + SOT[j * 128 + t] - dob);
        rv = cs + ALPHA_F * cso;  rov = cso;
        float ci  = fmaxf(0.0f, MARGIN_F + S[t * 128 + j] - db);
        float cio = fmaxf(0.0f, MARGIN_F + SOT[t * 128 + j] - dob);
        cv = ci + ALPHA_F * cio;  cov = cio;
    }
    for (int off = 32; off; off >>= 1) {
        rv  = fmaxf(rv,  __shfl_down(rv,  off, 64));
        rov = fmaxf(rov, __shfl_down(rov, off, 64));
        cv  = fmaxf(cv,  __shfl_down(cv,  off, 64));
        cov = fmaxf(cov, __shfl_down(cov, off, 64));
    }
    if ((t & 63) == 0) {
        sh[0][t >> 6] = rv; sh[1][t >> 6] = rov;
        sh[2][t >> 6] = cv; sh[3][t >> 6] = cov;
    }
    __syncthreads();
    if (t == 0) {
        float a0 = fmaxf(sh[0][0], sh[0][1]) + fmaxf(sh[2][0], sh[2][1]);
        float a1 = fmaxf(sh[1][0], sh[1][1]) + fmaxf(sh[3][0], sh[3][1]);
        atomicAdd(&out[0], a0);
        atomicAdd(&out[1], a1);
    }
}

extern "C" void kernel_launch(void* const* d_in, const int* in_sizes, int n_in,
                              void* d_out, int out_size, void* d_ws, size_t ws_size,
                              hipStream_t stream) {
    const float* im  = (const float*)d_in[0];
    const float* s   = (const float*)d_in[1];
    const int*   s_l = (const int*)d_in[2];
    float* out = (float*)d_out;
    float* ws  = (float*)d_ws;

    float* inv_im  = ws;
    float* inv_cap = ws + 4608;
    float* S       = ws + 12288;
    float* SOT     = ws + 12288 + 16384;
    // bf16 conversion area after the 180224-byte float region
    unsigned short* im16 = (unsigned short*)((char*)d_ws + 180224);
    unsigned short* s16  = im16 + (size_t)N_IMAGE * N_REG * DIM;
    const size_t need = 180224 +
        ((size_t)N_IMAGE * N_REG * DIM + (size_t)N_IMAGE * MAX_WORD * DIM) * 2;
    const int fast = (ws_size >= need) ? 1 : 0;   // ws_size is call-invariant

    norms_kernel<<<dim3((4608 + 7680) / 4), dim3(256), 0, stream>>>(
        im, s, inv_im, inv_cap, out, fast, im16, s16);
    if (fast)
        pair_kernel<true><<<dim3(N_IMAGE, N_IMAGE / 4), dim3(256), 0, stream>>>(
            im, s, im16, s16, s_l, inv_im, inv_cap, S, SOT);
    else
        pair_kernel<false><<<dim3(N_IMAGE, N_IMAGE / 4), dim3(256), 0, stream>>>(
            im, s, im16, s16, s_l, inv_im, inv_cap, S, SOT);
    loss_kernel<<<dim3(N_IMAGE), dim3(128), 0, stream>>>(S, SOT, out);
}

// Round 2
// 283.563 us; speedup vs baseline: 1.1938x; 1.1011x over previous
//
#include <hip/hip_runtime.h>
#include <hip/hip_bf16.h>
#include <math.h>

#define N_IMAGE 128
#define N_REG   36
#define DIM     1024
#define MAX_WORD 60
#define OT_ITERS 20
#define MARGIN_F 0.2f
#define ALPHA_F  0.1f
#define EPS_F    1e-12f

// fragment-major panel layout: [panel][c:16][h:2][q:4][l15:16][e:8] bf16
#define APAN  16384                    // elems per 16-row x 1024-col panel
#define AIMG  (3 * APAN)               // 3 panels per image (48 rows, 36 valid)
#define BCAP  (4 * APAN)               // 4 panels per caption (64 rows, 60 valid)

typedef short bf16x8 __attribute__((ext_vector_type(8)));
typedef float f32x4  __attribute__((ext_vector_type(4)));
typedef float f32x2  __attribute__((ext_vector_type(2)));

// ---------------- helpers ----------------

__device__ __forceinline__ unsigned int pkbf2(float a, float b) {
    union { __hip_bfloat162 h2; unsigned int u; } cv;
    cv.h2 = __float22bfloat162_rn(make_float2(a, b));
    return cv.u;
}
__device__ __forceinline__ float lo16(unsigned int u) { return __int_as_float((int)(u << 16)); }
__device__ __forceinline__ float hi16(unsigned int u) { return __int_as_float((int)(u & 0xFFFF0000u)); }

#define SWZ(x, pat) __int_as_float(__builtin_amdgcn_ds_swizzle(__float_as_int(x), (pat)))
#define BPERM(a, x) __int_as_float(__builtin_amdgcn_ds_bpermute((a), __float_as_int(x)))
#define DPPADD(x, ctrl) \
    ((x) + __int_as_float(__builtin_amdgcn_update_dpp(0, __float_as_int(x), (ctrl), 0xf, 0xf, true)))

// 16-lane group sum (all 16 lanes get the sum). Pure DPP/VALU.
__device__ __forceinline__ float bfly16_sum(float x) {
    x = DPPADD(x, 0xB1);    // quad_perm ^1
    x = DPPADD(x, 0x4E);    // quad_perm ^2
    x = DPPADD(x, 0x124);   // row_ror:4
    x = DPPADD(x, 0x128);   // row_ror:8
    return x;
}
__device__ __forceinline__ float bfly64_sum(float x, int xaddr) {
    x = bfly16_sum(x);
    x += SWZ(x, 0x401F);   // ^16
    x += BPERM(xaddr, x);  // ^32
    return x;
}

// ------- pack: f32 row-major -> fragment-major bf16 panels + inv norms + out zero -------
// grid: 128*3 im panels + 128*4 s panels = 896 blocks x 256 threads.
// thread = (w = tid>>6 picks c-group, q, l15). Panel rows on l15; pad rows zero-filled.

__global__ __launch_bounds__(256) void pack_kernel(
    const float* __restrict__ im, const float* __restrict__ s,
    float* __restrict__ inv_im, float* __restrict__ inv_cap,
    float* __restrict__ out,
    unsigned short* __restrict__ imp, unsigned short* __restrict__ sp) {

    const int pid = blockIdx.x;
    const int tid = threadIdx.x;
    if (pid == 0 && tid == 0) { out[0] = 0.0f; out[1] = 0.0f; }

    const int w = tid >> 6, lane = tid & 63, q = lane >> 4, l15 = lane & 15;
    const bool isim = (pid < 384);
    int obj, p, nvalid;
    const float* src;
    unsigned short* dst;
    if (isim) {
        obj = pid / 3; p = pid % 3;
        src = im + (size_t)obj * 36 * DIM;
        dst = imp + (size_t)obj * AIMG + (size_t)p * APAN;
        nvalid = 36;
    } else {
        const int k = pid - 384;
        obj = k >> 2; p = k & 3;
        src = s + (size_t)obj * 60 * DIM;
        dst = sp + (size_t)obj * BCAP + (size_t)p * APAN;
        nvalid = 60;
    }
    const int row = p * 16 + l15;
    const bool valid = (row < nvalid);

    float ss = 0.0f;
    #pragma unroll
    for (int i = 0; i < 4; ++i) {
        const int c = w * 4 + i;
        #pragma unroll
        for (int h = 0; h < 2; ++h) {
            float4 v0 = make_float4(0.f, 0.f, 0.f, 0.f), v1 = v0;
            if (valid) {
                const float* rp = src + (size_t)row * DIM + c * 64 + h * 32 + q * 8;
                v0 = *(const float4*)rp;
                v1 = *(const float4*)(rp + 4);
            }
            ss += v0.x * v0.x + v0.y * v0.y + v0.z * v0.z + v0.w * v0.w
                + v1.x * v1.x + v1.y * v1.y + v1.z * v1.z + v1.w * v1.w;
            uint4 o;
            o.x = pkbf2(v0.x, v0.y); o.y = pkbf2(v0.z, v0.w);
            o.z = pkbf2(v1.x, v1.y); o.w = pkbf2(v1.z, v1.w);
            *(uint4*)(dst + (size_t)c * 1024 + h * 512 + q * 128 + l15 * 8) = o;
        }
    }
    // row sum-sq: reduce over q (lane bits 4,5), then across the 4 waves via LDS
    const int xaddr = ((lane ^ 32) << 2);
    ss += SWZ(ss, 0x401F);
    ss += BPERM(xaddr, ss);
    __shared__ float sh[4][16];
    if (lane < 16) sh[w][lane] = ss;
    __syncthreads();
    if (tid < 16) {
        const float t = sh[0][tid] + sh[1][tid] + sh[2][tid] + sh[3][tid];
        const int r = p * 16 + tid;
        if (r < nvalid) {
            const float inv = 1.0f / (sqrtf(t) + EPS_F);
            if (isim) inv_im[obj * 36 + r] = inv;
            else      inv_cap[obj * 60 + r] = inv;
        }
    }
}

// ------- norms (fallback path only: inv norms from f32, zero d_out) -------

__global__ void norms_kernel(const float* __restrict__ im, const float* __restrict__ s,
                             float* __restrict__ inv_im, float* __restrict__ inv_cap,
                             float* __restrict__ out) {
    if (blockIdx.x == 0 && threadIdx.x == 0) { out[0] = 0.0f; out[1] = 0.0f; }
    const int NIM = N_IMAGE * N_REG;     // 4608
    const int NS  = N_IMAGE * MAX_WORD;  // 7680
    int row  = blockIdx.x * 4 + (threadIdx.x >> 6);
    int lane = threadIdx.x & 63;
    if (row >= NIM + NS) return;
    const bool isim = (row < NIM);
    const float* base = isim ? (im + (size_t)row * DIM)
                             : (s  + (size_t)(row - NIM) * DIM);
    const float4* b4 = (const float4*)base;
    float acc = 0.0f;
    for (int k = lane; k < DIM / 4; k += 64) {
        float4 v = b4[k];
        acc += v.x * v.x + v.y * v.y + v.z * v.z + v.w * v.w;
    }
    for (int off = 32; off; off >>= 1) acc += __shfl_down(acc, off, 64);
    if (lane == 0) {
        float inv = 1.0f / (sqrtf(acc) + EPS_F);
        if (isim) inv_im[row] = inv;
        else      inv_cap[row - NIM] = inv;
    }
}

// ---------------- shared OT epilogue (identical math to round-1) ----------------

template <int CT>
__device__ __forceinline__ void ot_epilogue(
    f32x4 (&acc)[3 * CT], const float* invImS, const float* invCapS,
    int cap, int b0, int m, float* __restrict__ S, float* __restrict__ SOT) {

    const int tid  = threadIdx.x;
    const int lane = tid & 63;
    const int wv   = tid >> 6;
    const int q    = lane >> 4;
    const int l15  = lane & 15;
    const int xaddr = ((lane ^ 32) << 2);
    const float mf    = (float)m;
    const float inv_m = 1.0f / mf;

    constexpr int PK = (CT + 1) / 2;
    float icap[CT]; bool vw[CT];
    #pragma unroll
    for (int ct = 0; ct < CT; ++ct) {
        const int w = ct * 16 + l15;
        vw[ct]   = (w < m);
        icap[ct] = (w < 60) ? invCapS[w] : 0.0f;
    }

    unsigned int apk[12][PK];    // A = exp(-2C), bf16-packed; j = rt*4+p, row = rt*16+q*4+p
    float mxv[CT];
    #pragma unroll
    for (int ct = 0; ct < CT; ++ct) mxv[ct] = -3e38f;

    #pragma unroll
    for (int j = 0; j < 12; ++j) {
        const int rt = j >> 2, p = j & 3;
        const int r  = rt * 16 + q * 4 + p;                  // < 48
        const bool rowok = (rt < 2) || (q == 0);             // r < 36
        const float iir = rowok ? invImS[wv * 36 + (r < 36 ? r : 0)] : 0.0f;
        float av[CT];
        #pragma unroll
        for (int ct = 0; ct < CT; ++ct) {
            const float Mv = acc[rt * CT + ct][p];
            mxv[ct] = fmaxf(mxv[ct], rowok ? Mv : -3e38f);
            const float cv = 1.0f - Mv * iir * icap[ct];     // C = 1 - cos
            const bool ok  = rowok && vw[ct];
            av[ct] = ok ? __expf(-2.0f * cv) : 0.0f;         // A = exp(-C/beta)
        }
        #pragma unroll
        for (int pk = 0; pk < PK; ++pk)
            apk[j][pk] = pkbf2(av[2 * pk], (2 * pk + 1 < CT) ? av[2 * pk + 1] : 0.0f);
    }

    // ---- row-compress 12 -> 9 j-slots (48 padded rows -> exactly 36) ----
    {
        const int baddr = l15 << 2;
        #pragma unroll
        for (int pk = 0; pk < PK; ++pk) {
            const int r0 = __builtin_amdgcn_ds_bpermute(baddr, (int)apk[8][pk]);
            const int r1 = __builtin_amdgcn_ds_bpermute(baddr, (int)apk[9][pk]);
            const int r2 = __builtin_amdgcn_ds_bpermute(baddr, (int)apk[10][pk]);
            const int r3 = __builtin_amdgcn_ds_bpermute(baddr, (int)apk[11][pk]);
            const int lo = (q & 1) ? r1 : r0;
            const int hi = (q & 1) ? r3 : r2;
            apk[8][pk] = (unsigned int)((q & 2) ? hi : lo);
        }
    }

    const int b = b0 + wv;
    // ---- MISA: mean_w max_r M ----
    {
        float sp = 0.0f;
        #pragma unroll
        for (int ct = 0; ct < CT; ++ct) {
            float v = mxv[ct];
            v = fmaxf(v, SWZ(v, 0x401F));
            v = fmaxf(v, BPERM(xaddr, v));
            sp += vw[ct] ? v : 0.0f;
        }
        sp = bfly64_sum(sp, xaddr);      // = 4 * sum_w colmax (q-replicated)
        if (lane == 0) S[(size_t)b * N_IMAGE + cap] = sp * inv_m * 0.25f;
    }

    // ---- IPOT: 20 iterations, 9 row-slots, packed-f32 (v_pk_*) math ----
    f32x2 t2[9][PK];
    f32x2 sig2[PK];
    #pragma unroll
    for (int pk = 0; pk < PK; ++pk) {
        const bool v0 = vw[2 * pk];
        const bool v1 = (2 * pk + 1 < CT) && vw[2 * pk + 1];
        sig2[pk].x = v0 ? inv_m : 0.0f;
        sig2[pk].y = v1 ? inv_m : 0.0f;
        #pragma unroll
        for (int j = 0; j < 9; ++j) {
            t2[j][pk].x = v0 ? mf : 0.0f;
            t2[j][pk].y = v1 ? mf : 0.0f;
        }
    }

    for (int it = 0; it < OT_ITERS; ++it) {
        f32x2 s2[PK], csum[PK];
        #pragma unroll
        for (int pk = 0; pk < PK; ++pk) {
            s2[pk]   = sig2[pk] * sig2[pk];
            csum[pk] = (f32x2){0.0f, 0.0f};
        }
        #pragma unroll
        for (int j = 0; j < 9; ++j) {
            f32x2 at[PK];
            #pragma unroll
            for (int pk = 0; pk < PK; ++pk) {
                f32x2 a2;
                a2.x = lo16(apk[j][pk]);
                a2.y = hi16(apk[j][pk]);
                at[pk] = a2 * t2[j][pk];
            }
            f32x2 u2 = at[0] * s2[0];
            #pragma unroll
            for (int pk = 1; pk < PK; ++pk) u2 += at[pk] * s2[pk];
            const float R  = bfly16_sum(u2.x + u2.y);
            const float dl = __builtin_amdgcn_rcpf(36.0f * R);
            f32x2 dl2; dl2.x = dl; dl2.y = dl;
            #pragma unroll
            for (int pk = 0; pk < PK; ++pk) {
                const f32x2 tn = at[pk] * (dl2 * sig2[pk]);
                t2[j][pk] = tn;
                csum[pk] += tn;
            }
        }
        #pragma unroll
        for (int pk = 0; pk < PK; ++pk) {
            float cx = csum[pk].x;
            cx += SWZ(cx, 0x401F);
            cx += BPERM(xaddr, cx);
            float cy = csum[pk].y;
            cy += SWZ(cy, 0x401F);
            cy += BPERM(xaddr, cy);
            const bool v0 = vw[2 * pk];
            const bool v1 = (2 * pk + 1 < CT) && vw[2 * pk + 1];
            sig2[pk].x = v0 ? __builtin_amdgcn_rcpf(mf * cx) : 0.0f;
            sig2[pk].y = v1 ? __builtin_amdgcn_rcpf(mf * cy) : 0.0f;
        }
    }

    // ---- sims_ot = -Σ C∘T ;  C = -0.5 ln(A), T = t*sig ----
    {
        float pp = 0.0f;
        #pragma unroll
        for (int j = 0; j < 9; ++j) {
            #pragma unroll
            for (int pk = 0; pk < PK; ++pk) {
                const float ax = lo16(apk[j][pk]);
                const float cvx = -0.5f * __logf(fmaxf(ax, 1e-30f));
                pp = fmaf(cvx, t2[j][pk].x * sig2[pk].x, pp);
                if (2 * pk + 1 < CT) {
                    const float ay = hi16(apk[j][pk]);
                    const float cvy = -0.5f * __logf(fmaxf(ay, 1e-30f));
                    pp = fmaf(cvy, t2[j][pk].y * sig2[pk].y, pp);
                }
            }
        }
        pp = bfly64_sum(pp, xaddr);
        if (lane == 0) SOT[(size_t)b * N_IMAGE + cap] = -pp;
    }
}

// ---------------- fast pair body: LDS-free GEMM, coalesced fragment loads ----------------
// Fragment (rt|ct, h, c) for lane (q,l15): 16B at panelbase + c*2048B + h*1024B + (q*128+l15*8)*2B
// -> one fully-coalesced global_load_dwordx4 per fragment. Software-pipelined one h-group ahead.

template <int CT>
__device__ __forceinline__ void pair_body_fast(
    const unsigned short* __restrict__ imp, const unsigned short* __restrict__ sp,
    const float* invImS, const float* invCapS,
    int cap, int b0, int m,
    float* __restrict__ S, float* __restrict__ SOT) {

    const int tid  = threadIdx.x;
    const int lane = tid & 63;
    const int wv   = tid >> 6;
    const int q    = lane >> 4;
    const int l15  = lane & 15;

    const unsigned short* Ab = imp + (size_t)(b0 + wv) * AIMG + (q * 128 + l15 * 8);
    const unsigned short* Bb = sp  + (size_t)cap * BCAP        + (q * 128 + l15 * 8);

    f32x4 acc[3 * CT];
    #pragma unroll
    for (int t = 0; t < 3 * CT; ++t) acc[t] = (f32x4){0.f, 0.f, 0.f, 0.f};

    bf16x8 a0[3], bf0[CT], a1[3], bf1[CT];
    // preload c=0, h=0
    #pragma unroll
    for (int rt = 0; rt < 3; ++rt) a0[rt] = *(const bf16x8*)(Ab + rt * APAN);
    #pragma unroll
    for (int ct = 0; ct < CT; ++ct) bf0[ct] = *(const bf16x8*)(Bb + ct * APAN);

    #pragma unroll 1
    for (int c = 0; c < 16; ++c) {
        const unsigned short* Ac = Ab + c * 1024;
        const unsigned short* Bc = Bb + c * 1024;
        // h=1 loads for this c
        #pragma unroll
        for (int rt = 0; rt < 3; ++rt) a1[rt] = *(const bf16x8*)(Ac + rt * APAN + 512);
        #pragma unroll
        for (int ct = 0; ct < CT; ++ct) bf1[ct] = *(const bf16x8*)(Bc + ct * APAN + 512);
        // MFMA h=0
        #pragma unroll
        for (int rt = 0; rt < 3; ++rt)
            #pragma unroll
            for (int ct = 0; ct < CT; ++ct)
                acc[rt * CT + ct] = __builtin_amdgcn_mfma_f32_16x16x32_bf16(
                    a0[rt], bf0[ct], acc[rt * CT + ct], 0, 0, 0);
        // h=0 loads for next c (clamped: c=15 reloads itself, result unused)
        const int cn = (c < 15) ? c + 1 : 15;
        const unsigned short* An = Ab + cn * 1024;
        const unsigned short* Bn = Bb + cn * 1024;
        #pragma unroll
        for (int rt = 0; rt < 3; ++rt) a0[rt] = *(const bf16x8*)(An + rt * APAN);
        #pragma unroll
        for (int ct = 0; ct < CT; ++ct) bf0[ct] = *(const bf16x8*)(Bn + ct * APAN);
        // MFMA h=1
        #pragma unroll
        for (int rt = 0; rt < 3; ++rt)
            #pragma unroll
            for (int ct = 0; ct < CT; ++ct)
                acc[rt * CT + ct] = __builtin_amdgcn_mfma_f32_16x16x32_bf16(
                    a1[rt], bf1[ct], acc[rt * CT + ct], 0, 0, 0);
    }

    __syncthreads();   // invImS/invCapS ready
    ot_epilogue<CT>(acc, invImS, invCapS, cap, b0, m, S, SOT);
}

__global__ __launch_bounds__(256, 4)
void pair_fast(const unsigned short* __restrict__ imp,
               const unsigned short* __restrict__ sp,
               const int* __restrict__ s_l,
               const float* __restrict__ inv_im, const float* __restrict__ inv_cap,
               float* __restrict__ S, float* __restrict__ SOT) {
    const int cap = blockIdx.x;
    const int b0  = blockIdx.y * 4;
    const int tid = threadIdx.x;

    __shared__ float invImS[144];
    __shared__ float invCapS[60];
    if (tid < 144) invImS[tid] = inv_im[b0 * 36 + tid];
    else if (tid < 204) invCapS[tid - 144] = inv_cap[cap * 60 + (tid - 144)];

    const int m  = s_l[cap];
    const int CT = __builtin_amdgcn_readfirstlane((m + 15) >> 4);   // 1..4
    switch (CT) {
    case 1: pair_body_fast<1>(imp, sp, invImS, invCapS, cap, b0, m, S, SOT); break;
    case 2: pair_body_fast<2>(imp, sp, invImS, invCapS, cap, b0, m, S, SOT); break;
    case 3: pair_body_fast<3>(imp, sp, invImS, invCapS, cap, b0, m, S, SOT); break;
    default: pair_body_fast<4>(imp, sp, invImS, invCapS, cap, b0, m, S, SOT); break;
    }
}

// ---------------- fallback pair body (f32 inputs, LDS staging; round-1 structure) ----

template <int CT>
__device__ __forceinline__ void pair_body_slow(
    const float* __restrict__ im, const float* __restrict__ s,
    char* smem, const float* invImS, const float* invCapS,
    int cap, int b0, int m,
    float* __restrict__ S, float* __restrict__ SOT) {

    const int tid  = threadIdx.x;
    const int lane = tid & 63;
    const int wv   = tid >> 6;
    const int q    = lane >> 4;
    const int l15  = lane & 15;
    const int q4   = tid & 15;
    const int row0 = tid >> 4;

    const char* sA = smem;
    const char* sB = smem + 27648;

    f32x4 acc[3 * CT];
    #pragma unroll
    for (int t = 0; t < 3 * CT; ++t) acc[t] = (f32x4){0.f, 0.f, 0.f, 0.f};

    for (int c = 0; c < 16; ++c) {
        const int col = c * 64 + q4 * 4;
        #pragma unroll
        for (int img = 0; img < 4; ++img) {
            #pragma unroll
            for (int j = 0; j < 3; ++j) {
                const int r = row0 + 16 * j;
                if (j < 2 || row0 < 4) {
                    const size_t ro = (size_t)(b0 * 36 + img * 36 + r) * 1024 + col;
                    float4 v = *(const float4*)(im + ro);
                    uint2 w2; w2.x = pkbf2(v.x, v.y); w2.y = pkbf2(v.z, v.w);
                    *(uint2*)(smem + (img * 48 + r) * 144 + q4 * 8) = w2;
                }
            }
        }
        #pragma unroll
        for (int j = 0; j < CT; ++j) {
            const int r = row0 + 16 * j;
            if (CT < 4 || j < 3 || row0 < 12) {
                const size_t ro = (size_t)(cap * 60 + r) * 1024 + col;
                float4 v = *(const float4*)(s + ro);
                uint2 w2; w2.x = pkbf2(v.x, v.y); w2.y = pkbf2(v.z, v.w);
                *(uint2*)(smem + (192 + r) * 144 + q4 * 8) = w2;
            }
        }
        __syncthreads();
        #pragma unroll
        for (int h = 0; h < 2; ++h) {
            bf16x8 bfr[CT];
            #pragma unroll
            for (int ct = 0; ct < CT; ++ct)
                bfr[ct] = *(const bf16x8*)(sB + (ct * 16 + l15) * 144 + h * 64 + q * 16);
            #pragma unroll
            for (int rt = 0; rt < 3; ++rt) {
                bf16x8 afr = *(const bf16x8*)(sA + (wv * 48 + rt * 16 + l15) * 144 + h * 64 + q * 16);
                #pragma unroll
                for (int ct = 0; ct < CT; ++ct)
                    acc[rt * CT + ct] = __builtin_amdgcn_mfma_f32_16x16x32_bf16(
                        afr, bfr[ct], acc[rt * CT + ct], 0, 0, 0);
            }
        }
        __syncthreads();
    }
    ot_epilogue<CT>(acc, invImS, invCapS, cap, b0, m, S, SOT);
}

__global__ __launch_bounds__(256, 4)
void pair_slow(const float* __restrict__ im, const float* __restrict__ s,
               const int* __restrict__ s_l,
               const float* __restrict__ inv_im, const float* __restrict__ inv_cap,
               float* __restrict__ S, float* __restrict__ SOT) {
    const int cap = blockIdx.x;
    const int b0  = blockIdx.y * 4;
    const int tid = threadIdx.x;

    __shared__ __align__(16) char smem[36864];
    __shared__ float invImS[144];
    __shared__ float invCapS[60];

    if (tid < 144) invImS[tid] = inv_im[b0 * 36 + tid];
    else if (tid < 204) invCapS[tid - 144] = inv_cap[cap * 60 + (tid - 144)];

    const int m = s_l[cap];
    {
        float4 z = make_float4(0.f, 0.f, 0.f, 0.f);
        #pragma unroll
        for (int j = 0; j < 9; ++j)
            *(float4*)(smem + (tid + j * 256) * 16) = z;
    }
    __syncthreads();

    const int CT = __builtin_amdgcn_readfirstlane((m + 15) >> 4);
    switch (CT) {
    case 1: pair_body_slow<1>(im, s, smem, invImS, invCapS, cap, b0, m, S, SOT); break;
    case 2: pair_body_slow<2>(im, s, smem, invImS, invCapS, cap, b0, m, S, SOT); break;
    case 3: pair_body_slow<3>(im, s, smem, invImS, invCapS, cap, b0, m, S, SOT); break;
    default: pair_body_slow<4>(im, s, smem, invImS, invCapS, cap, b0, m, S, SOT); break;
    }
}

// ---------------- loss: 128 blocks, one per row/col pair, atomic accumulate ----

__global__ void loss_kernel(const float* __restrict__ S, const float* __restrict__ SOT,
                            float* __restrict__ out) {
    const int j = blockIdx.x;
    const int t = threadIdx.x;           // 128 threads
    __shared__ float sh[4][2];
    const float db  = S[j * 129];        // diag
    const float dob = SOT[j * 129];
    float rv = 0.f, rov = 0.f, cv = 0.f, cov = 0.f;
    if (t != j) {
        float cs  = fmaxf(0.0f, MARGIN_F + S[j * 128 + t] - db);
        float cso = fmaxf(0.0f, MARGIN_F + SOT[j * 128 + t] - dob);
        rv = cs + ALPHA_F * cso;  rov = cso;
        float ci  = fmaxf(0.0f, MARGIN_F + S[t * 128 + j] - db);
        float cio = fmaxf(0.0f, MARGIN_F + SOT[t * 128 + j] - dob);
        cv = ci + ALPHA_F * cio;  cov = cio;
    }
    for (int off = 32; off; off >>= 1) {
        rv  = fmaxf(rv,  __shfl_down(rv,  off, 64));
        rov = fmaxf(rov, __shfl_down(rov, off, 64));
        cv  = fmaxf(cv,  __shfl_down(cv,  off, 64));
        cov = fmaxf(cov, __shfl_down(cov, off, 64));
    }
    if ((t & 63) == 0) {
        sh[0][t >> 6] = rv; sh[1][t >> 6] = rov;
        sh[2][t >> 6] = cv; sh[3][t >> 6] = cov;
    }
    __syncthreads();
    if (t == 0) {
        float a0 = fmaxf(sh[0][0], sh[0][1]) + fmaxf(sh[2][0], sh[2][1]);
        float a1 = fmaxf(sh[1][0], sh[1][1]) + fmaxf(sh[3][0], sh[3][1]);
        atomicAdd(&out[0], a0);
        atomicAdd(&out[1], a1);
    }
}

extern "C" void kernel_launch(void* const* d_in, const int* in_sizes, int n_in,
                              void* d_out, int out_size, void* d_ws, size_t ws_size,
                              hipStream_t stream) {
    const float* im  = (const float*)d_in[0];
    const float* s   = (const float*)d_in[1];
    const int*   s_l = (const int*)d_in[2];
    float* out = (float*)d_out;
    float* ws  = (float*)d_ws;

    float* inv_im  = ws;
    float* inv_cap = ws + 4608;
    float* S       = ws + 12288;
    float* SOT     = ws + 12288 + 16384;
    // fragment-major bf16 panels after the 180224-byte float region
    unsigned short* imp = (unsigned short*)((char*)d_ws + 180224);
    unsigned short* sp  = imp + (size_t)N_IMAGE * AIMG;
    const size_t need = 180224 +
        ((size_t)N_IMAGE * AIMG + (size_t)N_IMAGE * BCAP) * 2;
    const int fast = (ws_size >= need) ? 1 : 0;   // ws_size is call-invariant

    if (fast) {
        pack_kernel<<<dim3(896), dim3(256), 0, stream>>>(
            im, s, inv_im, inv_cap, out, imp, sp);
        pair_fast<<<dim3(N_IMAGE, N_IMAGE / 4), dim3(256), 0, stream>>>(
            imp, sp, s_l, inv_im, inv_cap, S, SOT);
    } else {
        norms_kernel<<<dim3((4608 + 7680) / 4), dim3(256), 0, stream>>>(
            im, s, inv_im, inv_cap, out);
        pair_slow<<<dim3(N_IMAGE, N_IMAGE / 4), dim3(256), 0, stream>>>(
            im, s, s_l, inv_im, inv_cap, S, SOT);
    }
    loss_kernel<<<dim3(N_IMAGE), dim3(128), 0, stream>>>(S, SOT, out);
}